// Round 7
// baseline (272.429 us; speedup 1.0000x reference)
//
#include <hip/hip_runtime.h>
#include <hip/hip_bf16.h>

#define B_  2
#define S_  2048
#define D_  1024
#define H_  16
#define HD_ 64
#define M_  (B_*S_)   // 4096

using bf16x8 = __attribute__((ext_vector_type(8))) short;
using f32x4  = __attribute__((ext_vector_type(4))) float;

static __device__ __forceinline__ ushort f2bf(float f) {
    __hip_bfloat16 h = __float2bfloat16(f);
    return *reinterpret_cast<ushort*>(&h);
}
static __device__ __forceinline__ uint pk2bf(float a, float b) {
    __hip_bfloat162 h = __float22bfloat162_rn(make_float2(a, b));
    return *reinterpret_cast<uint*>(&h);
}

// async global->LDS, 16B per lane; LDS dest = wave-uniform base + lane*16 (no padding!)
#define GLDS16(gp, lp) __builtin_amdgcn_global_load_lds( \
    (const __attribute__((address_space(1))) void*)(gp), \
    (__attribute__((address_space(3))) void*)(lp), 16, 0, 0)

// ---- prep: z<4 -> weight transpose fp32[1024][1024] -> bf16 [N][K]; z==4 -> convert x ----
__global__ void prep(const float* __restrict__ x,
                     const float* __restrict__ wq, const float* __restrict__ wk,
                     const float* __restrict__ wv, const float* __restrict__ wo,
                     ushort* __restrict__ xb, ushort* __restrict__ wqkvT, ushort* __restrict__ woT) {
    if (blockIdx.z == 4) {   // convert x -> bf16
        int flat = blockIdx.y * 32 + blockIdx.x;              // 0..1023
        int tid = threadIdx.y * 32 + threadIdx.x;             // 0..255
        size_t base = ((size_t)flat * 256 + tid) * 16;
        #pragma unroll
        for (int i = 0; i < 4; i++) {
            float4 v = *reinterpret_cast<const float4*>(x + base + i*4);
            ushort4 o;
            o.x = f2bf(v.x); o.y = f2bf(v.y); o.z = f2bf(v.z); o.w = f2bf(v.w);
            *reinterpret_cast<ushort4*>(xb + base + i*4) = o;
        }
        return;
    }
    __shared__ float t[32][33];
    const float* src = blockIdx.z == 0 ? wq : (blockIdx.z == 1 ? wk : (blockIdx.z == 2 ? wv : wo));
    ushort* dst = blockIdx.z < 3 ? wqkvT + (size_t)blockIdx.z * 1024 * 1024 : woT;
    int c0 = blockIdx.x * 32, r0 = blockIdx.y * 32;
    int tx = threadIdx.x, ty = threadIdx.y;
    #pragma unroll
    for (int i = 0; i < 4; i++)
        t[ty + i*8][tx] = src[(size_t)(r0 + ty + i*8) * 1024 + c0 + tx];
    __syncthreads();
    #pragma unroll
    for (int i = 0; i < 4; i++)
        dst[(size_t)(c0 + ty + i*8) * 1024 + r0 + tx] = f2bf(t[tx][ty + i*8]);
}

// ---------------- GEMM: C = A(bf16 [M][K]) * Bt(bf16 [N][K])^T, tile MT x NT ---------
// MODE 0 (MT=NT=128): operand-swapped (reg-dim = N). Q/K -> [bh][s][hd] packed uint2;
//                     V -> written DIRECTLY TRANSPOSED to vt[bh][hd][s] (fuses transpose_v).
// MODE 1: reg-dim = M, fp32 out [M][Ndim] + bias.
template<int MODE, int MT, int NT, int MINW>
__launch_bounds__(256, MINW)
__global__ void gemm_bt(const ushort* __restrict__ A, const ushort* __restrict__ Bt,
                        int Ndim, int Kdim,
                        ushort* __restrict__ qout, ushort* __restrict__ kout, ushort* __restrict__ vtout,
                        const float* __restrict__ bq, const float* __restrict__ bk, const float* __restrict__ bv,
                        float* __restrict__ out, const float* __restrict__ bias)
{
    constexpr int MI = MT / 32, NI = NT / 32;
    __shared__ __align__(16) ushort As[MT][32];
    __shared__ __align__(16) ushort Bs[NT][32];
    const int tid  = threadIdx.x;
    const int lane = tid & 63, wave = tid >> 6;
    const int wm = wave & 1, wn = wave >> 1;
    const int m0 = blockIdx.y * MT, n0 = blockIdx.x * NT;
    const int g = lane >> 4, c = lane & 15;

    f32x4 acc[MI][NI];
    #pragma unroll
    for (int i = 0; i < MI; i++)
        #pragma unroll
        for (int j = 0; j < NI; j++) acc[i][j] = (f32x4){0.f, 0.f, 0.f, 0.f};

    const int lrow = lane >> 2;
    const int lcol = (lane & 3) * 8;

    for (int kt = 0; kt < Kdim; kt += 32) {
        #pragma unroll
        for (int ch = 0; ch < (MT + NT) / 64; ch++) {
            int cc_ = wave + ch * 4;
            if (cc_ < MT / 16)
                GLDS16(A  + (size_t)(m0 + cc_*16 + lrow) * Kdim + kt + lcol, &As[cc_*16][0]);
            else {
                int c2 = cc_ - MT / 16;
                GLDS16(Bt + (size_t)(n0 + c2*16 + lrow) * Kdim + kt + lcol, &Bs[c2*16][0]);
            }
        }
        __syncthreads();
        bf16x8 af[MI], bfr[NI];
        #pragma unroll
        for (int i = 0; i < MI; i++) af[i]  = *reinterpret_cast<const bf16x8*>(&As[wm*(MT/2) + i*16 + c][g*8]);
        #pragma unroll
        for (int j = 0; j < NI; j++) bfr[j] = *reinterpret_cast<const bf16x8*>(&Bs[wn*(NT/2) + j*16 + c][g*8]);
        if (MODE == 0) {
            #pragma unroll
            for (int i = 0; i < NI; i++)
                #pragma unroll
                for (int j = 0; j < MI; j++)
                    acc[i][j] = __builtin_amdgcn_mfma_f32_16x16x32_bf16(bfr[i], af[j], acc[i][j], 0, 0, 0);
        } else {
            #pragma unroll
            for (int i = 0; i < MI; i++)
                #pragma unroll
                for (int j = 0; j < NI; j++)
                    acc[i][j] = __builtin_amdgcn_mfma_f32_16x16x32_bf16(af[i], bfr[j], acc[i][j], 0, 0, 0);
        }
        __syncthreads();
    }

    const float qscale = 0.125f * 1.4426950408889634f;  // att_scale * log2e (exp2 softmax)
    if (MODE == 0) {
        #pragma unroll
        for (int i = 0; i < 4; i++) {
            int n = n0 + wn*64 + i*16 + g*4;          // quad base in N (wave-uniform 'which')
            int which = n >> 10;
            int cc = n & 1023;
            int h = cc >> 6, hd0 = cc & 63;
            float4 b4;
            if (which == 0)      b4 = *reinterpret_cast<const float4*>(bq + cc);
            else if (which == 1) b4 = *reinterpret_cast<const float4*>(bk + cc);
            else                 b4 = *reinterpret_cast<const float4*>(bv + cc);
            if (which == 2) {
                // V: store transposed -> vt[(b*16+h)*64 + hd][s]
                float bb[4] = {b4.x, b4.y, b4.z, b4.w};
                #pragma unroll
                for (int j = 0; j < 4; j++) {
                    int m = m0 + wm*64 + j*16 + c;
                    int b = m >> 11, s = m & 2047;
                    #pragma unroll
                    for (int r = 0; r < 4; r++)
                        vtout[((size_t)((b*H_ + h)*HD_) + hd0 + r) * S_ + s] =
                            f2bf(acc[i][j][r] + bb[r]);
                }
            } else {
                ushort* dstp = which == 0 ? qout : kout;
                float sc = which == 0 ? qscale : 1.f;
                #pragma unroll
                for (int j = 0; j < 4; j++) {
                    int m = m0 + wm*64 + j*16 + c;
                    int b = m >> 11, s = m & 2047;
                    uint2 o;
                    o.x = pk2bf((acc[i][j][0] + b4.x) * sc, (acc[i][j][1] + b4.y) * sc);
                    o.y = pk2bf((acc[i][j][2] + b4.z) * sc, (acc[i][j][3] + b4.w) * sc);
                    *reinterpret_cast<uint2*>(dstp + (((size_t)(b*H_ + h)) * S_ + s) * HD_ + hd0) = o;
                }
            }
        }
    } else {
        #pragma unroll
        for (int i = 0; i < MI; i++)
            #pragma unroll
            for (int j = 0; j < NI; j++)
                #pragma unroll
                for (int r = 0; r < 4; r++) {
                    int row = m0 + wm*(MT/2) + i*16 + g*4 + r;
                    int col = n0 + wn*(NT/2) + j*16 + c;
                    out[(size_t)row * Ndim + col] = acc[i][j][r] + bias[col];
                }
    }
}

// ---------------- flash attention v4: ZERO barriers, LDS holds only wave-private Ps ----
// K/Vt MFMA fragments come straight from global (L1/L2-served; all 4 waves read the
// same lines), software-pipelined one 32-key chunk ahead. No cross-barrier register
// state -> no scratch spills. Softmax: no-max exp2 domain; l reduced once at the end.
__launch_bounds__(256, 2)
__global__ void attn_kernel(const ushort* __restrict__ Q, const ushort* __restrict__ K,
                            const ushort* __restrict__ Vt, ushort* __restrict__ O)
{
    __shared__ __align__(16) ushort Ps[128][36];   // [q][key-chunk32], 18-dw stride (conflict-free)
    const int tid = threadIdx.x, lane = tid & 63, w = tid >> 6;
    const int g = lane >> 4, c = lane & 15;
    const int bh = blockIdx.y;
    const int q0 = blockIdx.x * 128;
    const ushort* __restrict__ Kp = K  + (size_t)bh * S_ * HD_;   // [s][hd]
    const ushort* __restrict__ Vp = Vt + (size_t)bh * HD_ * S_;   // [hd][s]

    // Q B-fragments (pre-scaled by 0.125*log2e) in registers for the whole kernel
    bf16x8 qf[2][2];
    #pragma unroll
    for (int sub = 0; sub < 2; sub++)
        #pragma unroll
        for (int ks = 0; ks < 2; ks++)
            qf[sub][ks] = *reinterpret_cast<const bf16x8*>(
                Q + ((size_t)bh * S_ + q0 + w*32 + sub*16 + c) * HD_ + ks*32 + g*8);

    f32x4 acc_o[2][4];
    float rs[2] = {0.f, 0.f};
    #pragma unroll
    for (int sub = 0; sub < 2; sub++)
        #pragma unroll
        for (int ct = 0; ct < 4; ct++) acc_o[sub][ct] = (f32x4){0.f, 0.f, 0.f, 0.f};

    // fragment loads for one 32-key chunk:
    //  kf[tp*2+ks] = K[key0+tp*16+c][ks*32+g*8..]   (A-op of S^T=K*Q^T)
    //  vf[ct]      = Vt[ct*16+c][key0+g*8..]        (B-op of O=P*V)
#define LOADF(CH, KD, VD) {                                                             \
        int key0 = (CH) * 32;                                                           \
        KD[0] = *reinterpret_cast<const bf16x8*>(Kp + (size_t)(key0 + c) * 64      + g*8); \
        KD[1] = *reinterpret_cast<const bf16x8*>(Kp + (size_t)(key0 + c) * 64 + 32 + g*8); \
        KD[2] = *reinterpret_cast<const bf16x8*>(Kp + (size_t)(key0 + 16 + c) * 64      + g*8); \
        KD[3] = *reinterpret_cast<const bf16x8*>(Kp + (size_t)(key0 + 16 + c) * 64 + 32 + g*8); \
        VD[0] = *reinterpret_cast<const bf16x8*>(Vp + (size_t)(     c) * S_ + key0 + g*8); \
        VD[1] = *reinterpret_cast<const bf16x8*>(Vp + (size_t)(16 + c) * S_ + key0 + g*8); \
        VD[2] = *reinterpret_cast<const bf16x8*>(Vp + (size_t)(32 + c) * S_ + key0 + g*8); \
        VD[3] = *reinterpret_cast<const bf16x8*>(Vp + (size_t)(48 + c) * S_ + key0 + g*8); \
    }

    bf16x8 kf[4], vf[4];
    LOADF(0, kf, vf);

    #pragma unroll 4
    for (int ch = 0; ch < 64; ch++) {          // 64 chunks x 32 keys = S
        bf16x8 kfn[4], vfn[4];
        int chn = ch < 63 ? ch + 1 : 63;       // last prefetch redundant but safe
        LOADF(chn, kfn, vfn);

        // ---- S^T chunk: D[key][q] (row=key g*4+r, col=q c); exp2; pack P ----
        #pragma unroll
        for (int tp = 0; tp < 2; tp++) {
            #pragma unroll
            for (int sub = 0; sub < 2; sub++) {
                f32x4 st = (f32x4){0.f, 0.f, 0.f, 0.f};
                st = __builtin_amdgcn_mfma_f32_16x16x32_bf16(kf[tp*2+0], qf[sub][0], st, 0, 0, 0);
                st = __builtin_amdgcn_mfma_f32_16x16x32_bf16(kf[tp*2+1], qf[sub][1], st, 0, 0, 0);
                float p0 = exp2f(st[0]), p1 = exp2f(st[1]);
                float p2 = exp2f(st[2]), p3 = exp2f(st[3]);
                rs[sub] += (p0 + p1) + (p2 + p3);
                uint2 pk;
                pk.x = pk2bf(p0, p1);
                pk.y = pk2bf(p2, p3);
                *reinterpret_cast<uint2*>(&Ps[w*32 + sub*16 + c][tp*16 + g*4]) = pk;
            }
        }
        // ---- O += P*V (Ps rows wave-private; same-wave DS ordering is in-order) ----
        bf16x8 pf0 = *reinterpret_cast<const bf16x8*>(&Ps[w*32 + c][g*8]);
        bf16x8 pf1 = *reinterpret_cast<const bf16x8*>(&Ps[w*32 + 16 + c][g*8]);
        #pragma unroll
        for (int ct = 0; ct < 4; ct++) {
            acc_o[0][ct] = __builtin_amdgcn_mfma_f32_16x16x32_bf16(pf0, vf[ct], acc_o[0][ct], 0, 0, 0);
            acc_o[1][ct] = __builtin_amdgcn_mfma_f32_16x16x32_bf16(pf1, vf[ct], acc_o[1][ct], 0, 0, 0);
        }
        #pragma unroll
        for (int i = 0; i < 4; i++) { kf[i] = kfn[i]; vf[i] = vfn[i]; }
    }
#undef LOADF

    // ---- reduce l per q-col (lane c owns q=c partials split over g) ----
    float l_i[2];
    #pragma unroll
    for (int sub = 0; sub < 2; sub++) {
        float t = rs[sub];
        t += __shfl_xor(t, 16);
        t += __shfl_xor(t, 32);
        l_i[sub] = t;
    }

    const int b = bh >> 4, h = bh & 15;
    #pragma unroll
    for (int sub = 0; sub < 2; sub++)
        #pragma unroll
        for (int r = 0; r < 4; r++) {
            float lr = 1.f / __shfl(l_i[sub], g*4 + r);
            int s = q0 + w*32 + sub*16 + g*4 + r;
            #pragma unroll
            for (int ct = 0; ct < 4; ct++)
                O[(size_t)(b*S_ + s) * 1024 + h*64 + ct*16 + c] = f2bf(acc_o[sub][ct][r] * lr);
        }
}

extern "C" void kernel_launch(void* const* d_in, const int* in_sizes, int n_in,
                              void* d_out, int out_size, void* d_ws, size_t ws_size,
                              hipStream_t stream)
{
    const float* x  = (const float*)d_in[0];
    const float* wq = (const float*)d_in[1];
    const float* bq = (const float*)d_in[2];
    const float* wk = (const float*)d_in[3];
    const float* bk = (const float*)d_in[4];
    const float* wv = (const float*)d_in[5];
    const float* bv = (const float*)d_in[6];
    const float* wo = (const float*)d_in[7];
    const float* bo = (const float*)d_in[8];
    float* out = (float*)d_out;

    char* ws = (char*)d_ws;
    ushort* xb    = (ushort*)(ws);                      // 8 MB  x bf16
    ushort* wqkvT = (ushort*)(ws + (8ull  << 20));      // 6 MB  [3072][1024]
    ushort* woT   = (ushort*)(ws + (14ull << 20));      // 2 MB
    ushort* qw    = (ushort*)(ws + (16ull << 20));      // 8 MB  [bh][s][hd]
    ushort* kw    = (ushort*)(ws + (24ull << 20));      // 8 MB  [bh][s][hd]
    ushort* vtw   = (ushort*)(ws + (32ull << 20));      // 8 MB  [bh][hd][s] (written by gemm1)
    ushort* ao    = (ushort*)(ws + (40ull << 20));      // 8 MB  attn out [4096][1024]

    prep<<<dim3(32, 32, 5), dim3(32, 8), 0, stream>>>(x, wq, wk, wv, wo, xb, wqkvT, woT);

    // QKV: M=4096, N=3072, K=1024 -> 768 blocks, 3/CU; V written pre-transposed
    gemm_bt<0, 128, 128, 3><<<dim3(24, 32), 256, 0, stream>>>(
        xb, wqkvT, 3072, 1024, qw, kw, vtw, bq, bk, bv, nullptr, nullptr);
    // attention (no barriers, Ps-only LDS)
    attn_kernel<<<dim3(16, 32), 256, 0, stream>>>(qw, kw, vtw, ao);
    // out proj: M=4096, N=1024, K=1024 -> 512 blocks, 2/CU
    gemm_bt<1, 128, 64, 2><<<dim3(16, 32), 256, 0, stream>>>(
        ao, woT, 1024, 1024, nullptr, nullptr, nullptr, nullptr, nullptr, nullptr,
        out, bo);
}